// Round 4
// baseline (162.161 us; speedup 1.0000x reference)
//
#include <hip/hip_runtime.h>

#define KK 4096
#define NN 11008
#define GRP 128
#define KW (KK / 2)          // 2048 int32 words per weight row (1 byte each)
#define NGRP (KK / GRP)      // 32 groups per row
#define KSPLIT 4             // waves per block, each covers KK/KSPLIT

using short8  = __attribute__((ext_vector_type(8))) short;
using float4v = __attribute__((ext_vector_type(4))) float;

// fp32 pair -> packed bf16x2 (RNE), lo in low 16 bits
static __device__ __forceinline__ unsigned int pack_bf16(float lo, float hi) {
    unsigned int ul = __builtin_bit_cast(unsigned int, lo);
    unsigned int uh = __builtin_bit_cast(unsigned int, hi);
    ul = (ul + 0x7FFFu + ((ul >> 16) & 1u)) >> 16;
    uh = (uh + 0x7FFFu + ((uh >> 16) & 1u)) & 0xFFFF0000u;
    return ul | uh;
}

__global__ __launch_bounds__(256) void qgemm_kernel(
    const float* __restrict__ A,        // (16, 4096) fp32 (fp16 upcast by harness)
    const int*   __restrict__ qweight,  // (11008, 2048) int32, 2 nibbles in low byte
    const float* __restrict__ scales,   // (11008, 32) fp32
    const float* __restrict__ zeros,    // (11008, 32) fp32
    const float* __restrict__ bias,     // (11008,) fp32
    float*       __restrict__ out)      // (16, 11008) fp32
{
    const int n0   = blockIdx.x * 16;
    const int wid  = threadIdx.x >> 6;   // 0..3 (K-split)
    const int lane = threadIdx.x & 63;
    const int nl   = lane & 15;          // n within tile; also m for A-frag
    const int quad = lane >> 4;          // 0..3
    const int n    = n0 + nl;

    const int kbase = wid * (KK / KSPLIT);   // 1024 k per wave

    float4v acc = {0.f, 0.f, 0.f, 0.f};

    const int*   qrow  = qweight + (size_t)n * KW;
    const float* Arowf = A + (size_t)nl * KK;

    // 8 groups of 128 k per wave; 4 MFMAs (32-k chunks) per group
    for (int g = 0; g < (KK / KSPLIT) / GRP; ++g) {
        const int grp = (kbase >> 7) + g;
        const float s_f = scales[n * NGRP + grp];
        const float z_f = zeros[n * NGRP + grp];
        const float c_f = -(128.0f + z_f) * s_f;   // fma(128+q, s, c) = (q-z)*s

        #pragma unroll
        for (int t = 0; t < 4; ++t) {
            const int k0 = kbase + g * GRP + t * 32 + quad * 8;

            // A fragment: A[m = lane&15][k = quad*8 + j], fp32 -> bf16 RNE
            float4v a0 = *(const float4v*)(Arowf + k0);
            float4v a1 = *(const float4v*)(Arowf + k0 + 4);
            union { short8 s8; unsigned int u[4]; } af;
            af.u[0] = pack_bf16(a0[0], a0[1]);
            af.u[1] = pack_bf16(a0[2], a0[3]);
            af.u[2] = pack_bf16(a1[0], a1[1]);
            af.u[3] = pack_bf16(a1[2], a1[3]);

            // 4 consecutive words = 8 weights (k0..k0+7) of row n, 16B
            int4 w4 = *(const int4*)(qrow + (k0 >> 1));
            const unsigned int ws[4] = {(unsigned int)w4.x, (unsigned int)w4.y,
                                        (unsigned int)w4.z, (unsigned int)w4.w};
            union { short8 s8; unsigned int u[4]; } b;
            #pragma unroll
            for (int i = 0; i < 4; ++i) {
                // low nibble -> bf16(128+lo) in low half, high nibble in high half
                unsigned int u = (ws[i] & 0xFu) | ((ws[i] << 12) & 0x000F0000u)
                               | 0x43004300u;
                float flo = __builtin_bit_cast(float, u << 16);         // 128+lo
                float fhi = __builtin_bit_cast(float, u & 0xFFFF0000u); // 128+hi
                float dlo = __builtin_fmaf(flo, s_f, c_f);
                float dhi = __builtin_fmaf(fhi, s_f, c_f);
                b.u[i] = pack_bf16(dlo, dhi);
            }
            acc = __builtin_amdgcn_mfma_f32_16x16x32_bf16(af.s8, b.s8, acc, 0, 0, 0);
        }
    }

    // Cross-wave (K-split) reduction through LDS.
    // C/D layout: row(m) = quad*4 + r, col(n) = lane&15   [m89-verified]
    __shared__ float red[KSPLIT][16][16];
    #pragma unroll
    for (int r = 0; r < 4; ++r)
        red[wid][quad * 4 + r][nl] = acc[r];
    __syncthreads();

    const int t  = threadIdx.x;        // 256 threads = 16x16 outputs
    const int m  = t >> 4;
    const int nn = t & 15;
    float sum = red[0][m][nn] + red[1][m][nn] + red[2][m][nn] + red[3][m][nn];
    sum += bias[n0 + nn];
    out[(size_t)m * NN + n0 + nn] = sum;   // fp32 output (harness upcasts fp16 -> fp32)
}

extern "C" void kernel_launch(void* const* d_in, const int* in_sizes, int n_in,
                              void* d_out, int out_size, void* d_ws, size_t ws_size,
                              hipStream_t stream) {
    const float* A       = (const float*)d_in[0];
    const int*   qweight = (const int*)d_in[1];
    const float* scales  = (const float*)d_in[2];
    const float* zeros   = (const float*)d_in[3];
    const float* bias    = (const float*)d_in[4];
    float*       out     = (float*)d_out;

    qgemm_kernel<<<dim3(NN / 16), dim3(256), 0, stream>>>(
        A, qweight, scales, zeros, bias, out);
}

// Round 5
// 155.536 us; speedup vs baseline: 1.0426x; 1.0426x over previous
//
#include <hip/hip_runtime.h>

#define KK 4096
#define NN 11008
#define GRP 128
#define KW (KK / 2)          // 2048 int32 words per weight row (1 byte each)
#define NGRP (KK / GRP)      // 32 groups per row
#define KSPLIT 8             // waves per block, each covers KK/KSPLIT = 512 k

using short8  = __attribute__((ext_vector_type(8))) short;
using float4v = __attribute__((ext_vector_type(4))) float;

// fp32 pair -> packed bf16x2 (RNE), lo in low 16 bits
static __device__ __forceinline__ unsigned int pack_bf16(float lo, float hi) {
    unsigned int ul = __builtin_bit_cast(unsigned int, lo);
    unsigned int uh = __builtin_bit_cast(unsigned int, hi);
    ul = (ul + 0x7FFFu + ((ul >> 16) & 1u)) >> 16;
    uh = (uh + 0x7FFFu + ((uh >> 16) & 1u)) & 0xFFFF0000u;
    return ul | uh;
}

__global__ __launch_bounds__(512) void qgemm_kernel(
    const float* __restrict__ A,        // (16, 4096) fp32 (fp16 upcast by harness)
    const int*   __restrict__ qweight,  // (11008, 2048) int32, 2 nibbles in low byte
    const float* __restrict__ scales,   // (11008, 32) fp32
    const float* __restrict__ zeros,    // (11008, 32) fp32
    const float* __restrict__ bias,     // (11008,) fp32
    float*       __restrict__ out)      // (16, 11008) fp32
{
    const int n0   = blockIdx.x * 16;
    const int wid  = threadIdx.x >> 6;   // 0..7 (K-split)
    const int lane = threadIdx.x & 63;
    const int nl   = lane & 15;          // n within tile; also m for A-frag
    const int quad = lane >> 4;          // 0..3
    const int n    = n0 + nl;

    const int kbase = wid * (KK / KSPLIT);   // 512 k per wave

    float4v acc = {0.f, 0.f, 0.f, 0.f};

    const int*   qrow  = qweight + (size_t)n * KW;
    const float* Arowf = A + (size_t)nl * KK;

    // 4 groups of 128 k per wave; 4 MFMAs (32-k chunks) per group.
    // Fully unrolled so the compiler hoists many 16B loads into flight
    // (round-4 post-mortem: VGPR=24 => almost no MLP, latency-bound at 26% occ).
    #pragma unroll
    for (int g = 0; g < (KK / KSPLIT) / GRP; ++g) {
        const int grp = (kbase >> 7) + g;
        const float s_f = scales[n * NGRP + grp];
        const float z_f = zeros[n * NGRP + grp];
        const float c_f = -(128.0f + z_f) * s_f;   // fma(128+q, s, c) = (q-z)*s

        // Stage all loads for the group first, then compute.
        float4v a0[4], a1[4];
        int4    w4[4];
        #pragma unroll
        for (int t = 0; t < 4; ++t) {
            const int k0 = kbase + g * GRP + t * 32 + quad * 8;
            a0[t] = *(const float4v*)(Arowf + k0);
            a1[t] = *(const float4v*)(Arowf + k0 + 4);
            w4[t] = *(const int4*)(qrow + (k0 >> 1));
        }

        #pragma unroll
        for (int t = 0; t < 4; ++t) {
            // A fragment: A[m = lane&15][k = quad*8 + j], fp32 -> bf16 RNE
            union { short8 s8; unsigned int u[4]; } af;
            af.u[0] = pack_bf16(a0[t][0], a0[t][1]);
            af.u[1] = pack_bf16(a0[t][2], a0[t][3]);
            af.u[2] = pack_bf16(a1[t][0], a1[t][1]);
            af.u[3] = pack_bf16(a1[t][2], a1[t][3]);

            const unsigned int ws[4] = {(unsigned int)w4[t].x, (unsigned int)w4[t].y,
                                        (unsigned int)w4[t].z, (unsigned int)w4[t].w};
            union { short8 s8; unsigned int u[4]; } b;
            #pragma unroll
            for (int i = 0; i < 4; ++i) {
                // low nibble -> bf16(128+lo) in low half, high nibble in high half
                unsigned int u = (ws[i] & 0xFu) | ((ws[i] << 12) & 0x000F0000u)
                               | 0x43004300u;
                float flo = __builtin_bit_cast(float, u << 16);         // 128+lo
                float fhi = __builtin_bit_cast(float, u & 0xFFFF0000u); // 128+hi
                float dlo = __builtin_fmaf(flo, s_f, c_f);
                float dhi = __builtin_fmaf(fhi, s_f, c_f);
                b.u[i] = pack_bf16(dlo, dhi);
            }
            acc = __builtin_amdgcn_mfma_f32_16x16x32_bf16(af.s8, b.s8, acc, 0, 0, 0);
        }
    }

    // Cross-wave (K-split) reduction through LDS.
    // C/D layout: row(m) = quad*4 + r, col(n) = lane&15   [m89-verified]
    __shared__ float red[KSPLIT][16][16];
    #pragma unroll
    for (int r = 0; r < 4; ++r)
        red[wid][quad * 4 + r][nl] = acc[r];
    __syncthreads();

    const int t = threadIdx.x;         // first 256 threads cover the 16x16 outputs
    if (t < 256) {
        const int m  = t >> 4;
        const int nn = t & 15;
        float sum = 0.f;
        #pragma unroll
        for (int w = 0; w < KSPLIT; ++w) sum += red[w][m][nn];
        sum += bias[n0 + nn];
        out[(size_t)m * NN + n0 + nn] = sum;
    }
}

extern "C" void kernel_launch(void* const* d_in, const int* in_sizes, int n_in,
                              void* d_out, int out_size, void* d_ws, size_t ws_size,
                              hipStream_t stream) {
    const float* A       = (const float*)d_in[0];
    const int*   qweight = (const int*)d_in[1];
    const float* scales  = (const float*)d_in[2];
    const float* zeros   = (const float*)d_in[3];
    const float* bias    = (const float*)d_in[4];
    float*       out     = (float*)d_out;

    qgemm_kernel<<<dim3(NN / 16), dim3(512), 0, stream>>>(
        A, qweight, scales, zeros, bias, out);
}

// Round 6
// 153.691 us; speedup vs baseline: 1.0551x; 1.0120x over previous
//
#include <hip/hip_runtime.h>

#define KK 4096
#define NN 11008
#define GRP 128
#define KW (KK / 2)          // 2048 int32 words per weight row (1 byte each)
#define NGRP (KK / GRP)      // 32 groups per row

using short8  = __attribute__((ext_vector_type(8))) short;
using float4v = __attribute__((ext_vector_type(4))) float;

// fp32 pair -> packed bf16x2 (RNE), lo in low 16 bits
static __device__ __forceinline__ unsigned int pack_bf16(float lo, float hi) {
    unsigned int ul = __builtin_bit_cast(unsigned int, lo);
    unsigned int uh = __builtin_bit_cast(unsigned int, hi);
    ul = (ul + 0x7FFFu + ((ul >> 16) & 1u)) >> 16;
    uh = (uh + 0x7FFFu + ((uh >> 16) & 1u)) & 0xFFFF0000u;
    return ul | uh;
}
// value of bf16(RNE(f)) as fp32
static __device__ __forceinline__ float bf16val(float f) {
    unsigned int u = __builtin_bit_cast(unsigned int, f);
    u = (u + 0x7FFFu + ((u >> 16) & 1u)) & 0xFFFF0000u;
    return __builtin_bit_cast(float, u);
}

// ws layout: [0,128KB) A as bf16 (16 x 4096, row-major); [128KB,+2KB) rowsum fp32 (16 x 32)
#define WS_RS_OFF 131072

// prep: blocks 0-31 convert A fp32->bf16 into ws; blocks 32-63 compute group row-sums
__global__ __launch_bounds__(256) void prep_kernel(
    const float* __restrict__ A, unsigned short* __restrict__ wsA,
    float* __restrict__ rowsum)
{
    const int b = blockIdx.x;
    if (b < 32) {
        const int idx = (b * 256 + threadIdx.x) * 8;   // 8 elements/thread
        float4v x0 = *(const float4v*)(A + idx);
        float4v x1 = *(const float4v*)(A + idx + 4);
        union { short8 s8; unsigned int u[4]; } p;
        p.u[0] = pack_bf16(x0[0], x0[1]);
        p.u[1] = pack_bf16(x0[2], x0[3]);
        p.u[2] = pack_bf16(x1[0], x1[1]);
        p.u[3] = pack_bf16(x1[2], x1[3]);
        *(short8*)(wsA + idx) = p.s8;
    } else {
        // 16 sums per block; 16 lanes cooperate per sum (8 elements each)
        const int sid = (b - 32) * 16 + (threadIdx.x >> 4);  // 0..511
        const int m = sid >> 5, g = sid & 31;
        const int j = threadIdx.x & 15;
        const float* p = A + (size_t)m * KK + g * GRP + j * 8;
        float4v x0 = *(const float4v*)p;
        float4v x1 = *(const float4v*)(p + 4);
        float sum = bf16val(x0[0]) + bf16val(x0[1]) + bf16val(x0[2]) + bf16val(x0[3])
                  + bf16val(x1[0]) + bf16val(x1[1]) + bf16val(x1[2]) + bf16val(x1[3]);
        sum += __shfl_xor(sum, 1, 16);
        sum += __shfl_xor(sum, 2, 16);
        sum += __shfl_xor(sum, 4, 16);
        sum += __shfl_xor(sum, 8, 16);
        if (j == 0) rowsum[sid] = sum;
    }
}

// Main: grid 1376 = 688 n-tiles x 2 k-halves; 256 threads = 4 waves, each wave 512 k.
// B fed to MFMA as exact bf16(128+q); scale applied per group on the accumulator;
// -(s*(128+z))*rowsum correction + bias applied in the epilogue; k-halves combine
// via fp32 atomicAdd (poison 0xAA = -3e-13, negligible).
__global__ __launch_bounds__(256) void qgemm_kernel(
    const int*   __restrict__ qweight,  // (11008, 2048) int32, 2 nibbles in low byte
    const float* __restrict__ scales,   // (11008, 32) fp32
    const float* __restrict__ zeros,    // (11008, 32) fp32
    const float* __restrict__ bias,     // (11008,) fp32
    const unsigned short* __restrict__ wsA,     // (16, 4096) bf16
    const float* __restrict__ rowsum,   // (16, 32) fp32
    float*       __restrict__ out)      // (16, 11008) fp32
{
    const int nt = blockIdx.x >> 1;
    const int kh = blockIdx.x & 1;
    const int n0 = nt * 16;
    const int wid  = threadIdx.x >> 6;
    const int lane = threadIdx.x & 63;
    const int nl   = lane & 15;
    const int quad = lane >> 4;
    const int n    = n0 + nl;

    const int kbase = kh * 2048 + wid * 512;  // this wave: 4 groups of 128 k
    const int g0    = kbase >> 7;             // first global group index

    const int*            qrow = qweight + (size_t)n * KW;
    const unsigned short* arow = wsA + (size_t)nl * KK;

    int4   wb[2][4];
    short8 ab[2][4];

    #pragma unroll
    for (int t = 0; t < 4; ++t) {
        const int k0 = kbase + t * 32 + quad * 8;
        wb[0][t] = *(const int4*)(qrow + (k0 >> 1));
        ab[0][t] = *(const short8*)(arow + k0);
    }
    float s_cur = scales[n * NGRP + g0];

    float4v acc = {0.f, 0.f, 0.f, 0.f};

    #pragma unroll
    for (int g = 0; g < 4; ++g) {
        const int cur = g & 1, nxt = cur ^ 1;
        float s_nxt = 0.f;
        if (g < 3) {   // prefetch next group while computing this one
            #pragma unroll
            for (int t = 0; t < 4; ++t) {
                const int k0 = kbase + (g + 1) * GRP + t * 32 + quad * 8;
                wb[nxt][t] = *(const int4*)(qrow + (k0 >> 1));
                ab[nxt][t] = *(const short8*)(arow + k0);
            }
            s_nxt = scales[n * NGRP + g0 + g + 1];
        }

        float4v accg = {0.f, 0.f, 0.f, 0.f};
        #pragma unroll
        for (int t = 0; t < 4; ++t) {
            const unsigned int w0 = (unsigned int)wb[cur][t].x;
            const unsigned int w1 = (unsigned int)wb[cur][t].y;
            const unsigned int w2 = (unsigned int)wb[cur][t].z;
            const unsigned int w3 = (unsigned int)wb[cur][t].w;
            union { short8 s8; unsigned int u[4]; } bf;
            // exact bf16(128+q) pair per word: no fma, no rounding
            bf.u[0] = (w0 & 0xFu) | ((w0 << 12) & 0x000F0000u) | 0x43004300u;
            bf.u[1] = (w1 & 0xFu) | ((w1 << 12) & 0x000F0000u) | 0x43004300u;
            bf.u[2] = (w2 & 0xFu) | ((w2 << 12) & 0x000F0000u) | 0x43004300u;
            bf.u[3] = (w3 & 0xFu) | ((w3 << 12) & 0x000F0000u) | 0x43004300u;
            accg = __builtin_amdgcn_mfma_f32_16x16x32_bf16(ab[cur][t], bf.s8, accg, 0, 0, 0);
        }
        #pragma unroll
        for (int r = 0; r < 4; ++r)
            acc[r] = __builtin_fmaf(s_cur, accg[r], acc[r]);
        s_cur = s_nxt;
    }

    // Cross-wave reduction. C/D layout: row(m)=quad*4+r, col(n)=lane&15 [m89]
    __shared__ float red[4][16][16];
    #pragma unroll
    for (int r = 0; r < 4; ++r)
        red[wid][quad * 4 + r][nl] = acc[r];
    __syncthreads();

    const int t  = threadIdx.x;
    const int m  = t >> 4;
    const int nn = t & 15;
    const int ng = n0 + nn;
    float val = red[0][m][nn] + red[1][m][nn] + red[2][m][nn] + red[3][m][nn];

    // correction for this k-half's 16 groups: -sum_g s*(128+z)*rowsum[m,g]
    const int gh0 = kh * 16;
    const float* srow = scales + (size_t)ng * NGRP + gh0;
    const float* zrow = zeros  + (size_t)ng * NGRP + gh0;
    const float* rsm  = rowsum + m * NGRP + gh0;
    float corr = 0.f;
    #pragma unroll
    for (int gg = 0; gg < 16; ++gg)
        corr = __builtin_fmaf(srow[gg] * (128.0f + zrow[gg]), rsm[gg], corr);
    val -= corr;
    if (kh == 0) val += bias[ng];
    atomicAdd(&out[(size_t)m * NN + ng], val);
}

extern "C" void kernel_launch(void* const* d_in, const int* in_sizes, int n_in,
                              void* d_out, int out_size, void* d_ws, size_t ws_size,
                              hipStream_t stream) {
    const float* A       = (const float*)d_in[0];
    const int*   qweight = (const int*)d_in[1];
    const float* scales  = (const float*)d_in[2];
    const float* zeros   = (const float*)d_in[3];
    const float* bias    = (const float*)d_in[4];
    float*       out     = (float*)d_out;

    unsigned short* wsA = (unsigned short*)d_ws;
    float* rowsum       = (float*)((char*)d_ws + WS_RS_OFF);

    prep_kernel<<<dim3(64), dim3(256), 0, stream>>>(A, wsA, rowsum);
    qgemm_kernel<<<dim3(2 * NN / 16), dim3(256), 0, stream>>>(
        qweight, scales, zeros, bias, wsA, rowsum, out);
}

// Round 7
// 151.018 us; speedup vs baseline: 1.0738x; 1.0177x over previous
//
#include <hip/hip_runtime.h>

#define KK 4096
#define NN 11008
#define NGRP 32
#define KW (KK / 2)        // 2048 int32 words per qweight row
#define ROWB 8192          // bytes per qweight row
#define LROW 528           // LDS bytes per staged row (512 + 16 pad)
#define TILEB (16 * LROW)  // one LDS buffer: 16 rows x 528 B
#define WS_RS_OFF 131072   // ws: [0,128K) A bf16; [128K,+2K) rowsums

using short8  = __attribute__((ext_vector_type(8))) short;
using float4v = __attribute__((ext_vector_type(4))) float;

static __device__ __forceinline__ unsigned int pack_bf16(float lo, float hi) {
    unsigned int ul = __builtin_bit_cast(unsigned int, lo);
    unsigned int uh = __builtin_bit_cast(unsigned int, hi);
    ul = (ul + 0x7FFFu + ((ul >> 16) & 1u)) >> 16;
    uh = (uh + 0x7FFFu + ((uh >> 16) & 1u)) & 0xFFFF0000u;
    return ul | uh;
}
static __device__ __forceinline__ float bf16val(float f) {
    unsigned int u = __builtin_bit_cast(unsigned int, f);
    u = (u + 0x7FFFu + ((u >> 16) & 1u)) & 0xFFFF0000u;
    return __builtin_bit_cast(float, u);
}

// prep: blocks 0-31 convert A fp32->bf16 into ws; blocks 32-63 compute group row-sums
__global__ __launch_bounds__(256) void prep_kernel(
    const float* __restrict__ A, unsigned short* __restrict__ wsA,
    float* __restrict__ rowsum)
{
    const int b = blockIdx.x;
    if (b < 32) {
        const int idx = (b * 256 + threadIdx.x) * 8;
        float4v x0 = *(const float4v*)(A + idx);
        float4v x1 = *(const float4v*)(A + idx + 4);
        union { short8 s8; unsigned int u[4]; } p;
        p.u[0] = pack_bf16(x0[0], x0[1]);
        p.u[1] = pack_bf16(x0[2], x0[3]);
        p.u[2] = pack_bf16(x1[0], x1[1]);
        p.u[3] = pack_bf16(x1[2], x1[3]);
        *(short8*)(wsA + idx) = p.s8;
    } else {
        const int sid = (b - 32) * 16 + (threadIdx.x >> 4);  // 0..511
        const int m = sid >> 5, g = sid & 31;
        const int j = threadIdx.x & 15;
        const float* p = A + (size_t)m * KK + g * 128 + j * 8;
        float4v x0 = *(const float4v*)p;
        float4v x1 = *(const float4v*)(p + 4);
        float sum = bf16val(x0[0]) + bf16val(x0[1]) + bf16val(x0[2]) + bf16val(x0[3])
                  + bf16val(x1[0]) + bf16val(x1[1]) + bf16val(x1[2]) + bf16val(x1[3]);
        sum += __shfl_xor(sum, 1, 16);
        sum += __shfl_xor(sum, 2, 16);
        sum += __shfl_xor(sum, 4, 16);
        sum += __shfl_xor(sum, 8, 16);
        if (j == 0) rowsum[sid] = sum;
    }
}

// Grid 1376 = 688 n-tiles x 2 k-halves, 256 threads = 4 waves.
// W staged via LDS with SEQUENTIAL global reads (round-6 post-mortem: the 16-row
// 64B-scatter pattern capped DRAM at ~2 TB/s). Raw nibble words live in LDS
// (2 B/k, same offsets as bf16); expansion to exact bf16(128+q) happens after
// the ds_read. Per step: wave reads two contiguous 512B row-runs; consecutive
// steps continue the same rows -> each row streams 4 KB sequentially.
__global__ __launch_bounds__(256) void qgemm_kernel(
    const int*   __restrict__ qweight,  // (11008, 2048) int32, 2 nibbles/word
    const float* __restrict__ scales,   // (11008, 32)
    const float* __restrict__ zeros,    // (11008, 32)
    const float* __restrict__ bias,     // (11008,)
    const unsigned short* __restrict__ wsA,   // (16, 4096) bf16
    const float* __restrict__ rowsum,   // (16, 32)
    float*       __restrict__ out)      // (16, 11008) fp32
{
    const int nt = blockIdx.x >> 1;
    const int kh = blockIdx.x & 1;
    const int n0 = nt * 16;
    const int wid  = threadIdx.x >> 6;
    const int lane = threadIdx.x & 63;
    const int nl   = lane & 15;
    const int quad = lane >> 4;

    __shared__ __align__(16) char lds[2 * TILEB];

    // Staging: wave wid owns rows [4*wid, 4*wid+4). Instr 0 covers rows
    // {4w + lane/32}, instr 1 rows {4w+2 + lane/32}; lane reads bytes
    // (lane%32)*16 of that row's 512B step-chunk -> two contiguous 512B runs.
    const char* qbase = (const char*)qweight + (size_t)n0 * ROWB + kh * 4096;
    const int   r0    = wid * 4 + (lane >> 5);
    const int   sbyte = (lane & 31) * 16;
    const char* gp0 = qbase + (size_t)r0 * ROWB + sbyte;
    const char* gp1 = qbase + (size_t)(r0 + 2) * ROWB + sbyte;
    char* lw0 = lds + r0 * LROW + sbyte;
    char* lw1 = lds + (r0 + 2) * LROW + sbyte;

    const unsigned short* arow = wsA + (size_t)nl * KK;
    const float*          srow = scales + (size_t)(n0 + nl) * NGRP + kh * 16;
    const char*           fr   = lds + nl * LROW + wid * 64 + quad * 16;

    int4 ra = *(const int4*)(gp0);
    int4 rb = *(const int4*)(gp1);

    float4v acc = {0.f, 0.f, 0.f, 0.f};

    for (int s = 0; s < 8; ++s) {
        const int bo = (s & 1) * TILEB;
        *(int4*)(lw0 + bo) = ra;
        *(int4*)(lw1 + bo) = rb;
        if (s < 7) {                       // prefetch next step's rows
            ra = *(const int4*)(gp0 + (s + 1) * 512);
            rb = *(const int4*)(gp1 + (s + 1) * 512);
        }
        __syncthreads();                   // tile s visible to all waves

        #pragma unroll
        for (int gg = 0; gg < 2; ++gg) {   // 2 groups per step; wave does chunk wid
            const int k0 = kh * 2048 + (s * 2 + gg) * 128 + wid * 32 + quad * 8;
            short8 a = *(const short8*)(arow + k0);
            int4 wv = *(const int4*)(fr + bo + gg * 256);
            union { short8 s8; unsigned int u[4]; } bf;
            const unsigned int w0 = (unsigned int)wv.x, w1 = (unsigned int)wv.y;
            const unsigned int w2 = (unsigned int)wv.z, w3 = (unsigned int)wv.w;
            bf.u[0] = (w0 & 0xFu) | ((w0 << 12) & 0x000F0000u) | 0x43004300u;
            bf.u[1] = (w1 & 0xFu) | ((w1 << 12) & 0x000F0000u) | 0x43004300u;
            bf.u[2] = (w2 & 0xFu) | ((w2 << 12) & 0x000F0000u) | 0x43004300u;
            bf.u[3] = (w3 & 0xFu) | ((w3 << 12) & 0x000F0000u) | 0x43004300u;
            float4v z4 = {0.f, 0.f, 0.f, 0.f};
            float4v accg = __builtin_amdgcn_mfma_f32_16x16x32_bf16(a, bf.s8, z4, 0, 0, 0);
            const float sg = srow[s * 2 + gg];
            #pragma unroll
            for (int r = 0; r < 4; ++r)
                acc[r] = __builtin_fmaf(sg, accg[r], acc[r]);
        }
    }

    // Cross-wave reduction. C/D layout: row(m)=quad*4+r, col(n)=lane&15 [m89]
    __shared__ float red[4][16][16];
    #pragma unroll
    for (int r = 0; r < 4; ++r)
        red[wid][quad * 4 + r][nl] = acc[r];
    __syncthreads();

    const int t  = threadIdx.x;
    const int m  = t >> 4;
    const int nn = t & 15;
    const int ng = n0 + nn;
    float val = red[0][m][nn] + red[1][m][nn] + red[2][m][nn] + red[3][m][nn];

    // correction: -sum_g s_g*(128+z_g)*rowsumA[m,g] over this k-half's 16 groups
    const int gh0 = kh * 16;
    const float* sr  = scales + (size_t)ng * NGRP + gh0;
    const float* zr  = zeros  + (size_t)ng * NGRP + gh0;
    const float* rsm = rowsum + m * NGRP + gh0;
    float corr = 0.f;
    #pragma unroll
    for (int gg = 0; gg < 16; ++gg)
        corr = __builtin_fmaf(sr[gg] * (128.0f + zr[gg]), rsm[gg], corr);
    val -= corr;
    if (kh == 0) val += bias[ng];
    atomicAdd(&out[(size_t)m * NN + ng], val);   // 0xAA poison = -3e-13, negligible
}

extern "C" void kernel_launch(void* const* d_in, const int* in_sizes, int n_in,
                              void* d_out, int out_size, void* d_ws, size_t ws_size,
                              hipStream_t stream) {
    const float* A       = (const float*)d_in[0];
    const int*   qweight = (const int*)d_in[1];
    const float* scales  = (const float*)d_in[2];
    const float* zeros   = (const float*)d_in[3];
    const float* bias    = (const float*)d_in[4];
    float*       out     = (float*)d_out;

    unsigned short* wsA = (unsigned short*)d_ws;
    float* rowsum       = (float*)((char*)d_ws + WS_RS_OFF);

    prep_kernel<<<dim3(64), dim3(256), 0, stream>>>(A, wsA, rowsum);
    qgemm_kernel<<<dim3(2 * NN / 16), dim3(256), 0, stream>>>(
        qweight, scales, zeros, bias, wsA, rowsum, out);
}

// Round 9
// 144.318 us; speedup vs baseline: 1.1236x; 1.0464x over previous
//
#include <hip/hip_runtime.h>

#define KK 4096
#define NN 11008
#define NGRP 32
#define KW 2048             // int32 words per qweight row
#define WS_RS_OFF 131072    // ws: [0,128K) A_perm bf16; [128K,+2K) rowsum
#define WS_SZ_OFF 139264    // [136K, +1.41M) SZ[n][g] = s*(128+z)

using short8  = __attribute__((ext_vector_type(8))) short;
using float4v = __attribute__((ext_vector_type(4))) float;

static __device__ __forceinline__ unsigned int pack_bf16(float lo, float hi) {
    unsigned int ul = __builtin_bit_cast(unsigned int, lo);
    unsigned int uh = __builtin_bit_cast(unsigned int, hi);
    ul = (ul + 0x7FFFu + ((ul >> 16) & 1u)) >> 16;
    uh = (uh + 0x7FFFu + ((uh >> 16) & 1u)) & 0xFFFF0000u;
    return ul | uh;
}
static __device__ __forceinline__ float bf16val(float f) {
    unsigned int u = __builtin_bit_cast(unsigned int, f);
    u = (u + 0x7FFFu + ((u >> 16) & 1u)) & 0xFFFF0000u;
    return __builtin_bit_cast(float, u);
}

// prep: b<32  -> A_perm: fragment-linear bf16 A. Chunk c = k/32 occupies
//                shorts [c*512, c*512+512); lane l holds A[l&15][c*32+(l>>4)*8..+8].
//       32-63 -> per-(m,group) row sums of bf16(A)
//       >=64  -> SZ[n][g] = scales*(128+zeros)
__global__ __launch_bounds__(256) void prep_kernel(
    const float* __restrict__ A, const float* __restrict__ scales,
    const float* __restrict__ zeros, unsigned short* __restrict__ wsA,
    float* __restrict__ rowsum, float* __restrict__ SZ)
{
    const int b = blockIdx.x, t = threadIdx.x;
    if (b < 32) {
        const int tid = b * 256 + t;          // 0..8191 = (chunk c)*64 + lane
        const int c = tid >> 6, l = tid & 63;
        const float* src = A + (size_t)(l & 15) * KK + c * 32 + (l >> 4) * 8;
        float4v x0 = *(const float4v*)src;
        float4v x1 = *(const float4v*)(src + 4);
        union { short8 s8; unsigned int u[4]; } p;
        p.u[0] = pack_bf16(x0[0], x0[1]);
        p.u[1] = pack_bf16(x0[2], x0[3]);
        p.u[2] = pack_bf16(x1[0], x1[1]);
        p.u[3] = pack_bf16(x1[2], x1[3]);
        *(short8*)(wsA + (size_t)tid * 8) = p.s8;
    } else if (b < 64) {
        const int sid = (b - 32) * 16 + (t >> 4);   // m*32+g
        const int m = sid >> 5, g = sid & 31, j = t & 15;
        const float* p = A + (size_t)m * KK + g * 128 + j * 8;
        float4v x0 = *(const float4v*)p;
        float4v x1 = *(const float4v*)(p + 4);
        float sum = bf16val(x0[0]) + bf16val(x0[1]) + bf16val(x0[2]) + bf16val(x0[3])
                  + bf16val(x1[0]) + bf16val(x1[1]) + bf16val(x1[2]) + bf16val(x1[3]);
        sum += __shfl_xor(sum, 1, 16);
        sum += __shfl_xor(sum, 2, 16);
        sum += __shfl_xor(sum, 4, 16);
        sum += __shfl_xor(sum, 8, 16);
        if (j == 0) rowsum[sid] = sum;
    } else {
        const int e0 = (b - 64) * 1024 + t * 4;     // 344 blocks cover 352256
        float4v s4 = *(const float4v*)(scales + e0);
        float4v z4 = *(const float4v*)(zeros + e0);
        float4v r;
        #pragma unroll
        for (int j = 0; j < 4; ++j) r[j] = s4[j] * (128.0f + z4[j]);
        *(float4v*)(SZ + e0) = r;
    }
}

// init_out: out[m][n] = bias[n] - sum_g SZ[n][g]*rowsum[m][g]  (plain store;
// overwrites poison; stream-ordered before qgemm's atomics)
__global__ __launch_bounds__(256) void init_out_kernel(
    const float* __restrict__ bias, const float* __restrict__ SZ,
    const float* __restrict__ rowsum, float* __restrict__ out)
{
    __shared__ float rs[16][32];
    const int t = threadIdx.x;
    rs[t >> 5][t & 31]       = rowsum[t];
    rs[(t >> 5) + 8][t & 31] = rowsum[t + 256];
    __syncthreads();
    const int n0 = blockIdx.x * 16;
    const int m = t >> 4, nn = t & 15, ng = n0 + nn;
    const float* szr = SZ + (size_t)ng * NGRP;
    float corr = 0.f;
    #pragma unroll
    for (int g = 0; g < 32; ++g)
        corr = __builtin_fmaf(szr[g], rs[m][g], corr);
    out[(size_t)m * NN + ng] = bias[ng] - corr;
}

// Hot kernel: 5504 blocks = 688 n-tiles x 8 k-slices, 4 waves/block, each wave
// ONE 128-k group: 8 independent loads -> 1 wait -> 4 MFMAs. No barrier in the
// load->MFMA path (R7: __syncthreads drains vmcnt(0) every step, killing MLP).
__global__ __launch_bounds__(256) void qgemm_kernel(
    const int*            __restrict__ qweight,  // (11008, 2048) words
    const float*          __restrict__ scales,   // (11008, 32)
    const unsigned short* __restrict__ aperm,    // fragment-linear bf16 A
    float*                __restrict__ out)      // (16, 11008) fp32
{
    const int nt = blockIdx.x >> 3, slice = blockIdx.x & 7;
    const int n0 = nt * 16;
    const int wid = threadIdx.x >> 6, lane = threadIdx.x & 63;
    const int nl = lane & 15, quad = lane >> 4;
    const int n = n0 + nl;
    const int g = slice * 4 + wid;               // this wave's group (0..31)

    const int* qrow = qweight + (size_t)n * KW + g * 64 + quad * 4;
    // group g = chunks g*4..g*4+3; chunk stride = 512 shorts  (R8 bug: was 2x)
    const unsigned short* ap = aperm + (size_t)g * 2048 + lane * 8;

    // issue all 8 vector loads + scale up front (independent)
    int4   w0 = *(const int4*)(qrow);
    int4   w1 = *(const int4*)(qrow + 16);
    int4   w2 = *(const int4*)(qrow + 32);
    int4   w3 = *(const int4*)(qrow + 48);
    short8 a0 = *(const short8*)(ap);
    short8 a1 = *(const short8*)(ap + 512);
    short8 a2 = *(const short8*)(ap + 1024);
    short8 a3 = *(const short8*)(ap + 1536);
    const float s = scales[n * NGRP + g];

    float4v acc = {0.f, 0.f, 0.f, 0.f};
    int4 wv[4] = {w0, w1, w2, w3};
    short8 av[4] = {a0, a1, a2, a3};
    #pragma unroll
    for (int t = 0; t < 4; ++t) {
        const unsigned int x0 = (unsigned int)wv[t].x, x1 = (unsigned int)wv[t].y;
        const unsigned int x2 = (unsigned int)wv[t].z, x3 = (unsigned int)wv[t].w;
        union { short8 s8; unsigned int u[4]; } bf;   // exact bf16(128+q)
        bf.u[0] = (x0 & 0xFu) | ((x0 << 12) & 0x000F0000u) | 0x43004300u;
        bf.u[1] = (x1 & 0xFu) | ((x1 << 12) & 0x000F0000u) | 0x43004300u;
        bf.u[2] = (x2 & 0xFu) | ((x2 << 12) & 0x000F0000u) | 0x43004300u;
        bf.u[3] = (x3 & 0xFu) | ((x3 << 12) & 0x000F0000u) | 0x43004300u;
        acc = __builtin_amdgcn_mfma_f32_16x16x32_bf16(av[t], bf.s8, acc, 0, 0, 0);
    }

    // scale is n-uniform per lane; apply, then 4-wave LDS reduce.
    __shared__ float red[4][16][16];
    #pragma unroll
    for (int r = 0; r < 4; ++r)
        red[wid][quad * 4 + r][nl] = s * acc[r];   // C/D: m=quad*4+r, n=nl [m89]
    __syncthreads();

    const int t = threadIdx.x;
    const int m = t >> 4, nn = t & 15;
    float val = red[0][m][nn] + red[1][m][nn] + red[2][m][nn] + red[3][m][nn];
    atomicAdd(&out[(size_t)m * NN + n0 + nn], val);  // 8 adds/output total
}

extern "C" void kernel_launch(void* const* d_in, const int* in_sizes, int n_in,
                              void* d_out, int out_size, void* d_ws, size_t ws_size,
                              hipStream_t stream) {
    const float* A       = (const float*)d_in[0];
    const int*   qweight = (const int*)d_in[1];
    const float* scales  = (const float*)d_in[2];
    const float* zeros   = (const float*)d_in[3];
    const float* bias    = (const float*)d_in[4];
    float*       out     = (float*)d_out;

    unsigned short* wsA = (unsigned short*)d_ws;
    float* rowsum       = (float*)((char*)d_ws + WS_RS_OFF);
    float* SZ           = (float*)((char*)d_ws + WS_SZ_OFF);

    prep_kernel<<<dim3(408), dim3(256), 0, stream>>>(A, scales, zeros, wsA, rowsum, SZ);
    init_out_kernel<<<dim3(688), dim3(256), 0, stream>>>(bias, SZ, rowsum, out);
    qgemm_kernel<<<dim3(5504), dim3(256), 0, stream>>>(qweight, scales, wsA, out);
}